// Round 2
// baseline (76.930 us; speedup 1.0000x reference)
//
#include <hip/hip_runtime.h>
#include <hip/hip_bf16.h>

#define N_ROWS 512
#define DFEAT  576

#if __has_builtin(__builtin_amdgcn_exp2f)
#define EXP2F __builtin_amdgcn_exp2f
#else
#define EXP2F exp2f
#endif

// ---------------------------------------------------------------------------
// Kernel 1: QKV GEMM.  OUT[w][n][i] = sum_k X[n,k] * W_w[i,k] + b_w[i]
// X: 512x576 fp32 row-major.  W: 576x576 fp32 row-major (out,in).
// fp32 output into workspace.  Tile 32x32, BK=32, TM=TN=2, 256 threads.
// ---------------------------------------------------------------------------
__global__ __launch_bounds__(256) void qkv_gemm_kernel(
    const float* __restrict__ X,
    const float* __restrict__ Wq, const float* __restrict__ Bq,
    const float* __restrict__ Wk, const float* __restrict__ Bk,
    const float* __restrict__ Wv, const float* __restrict__ Bv,
    float* __restrict__ out)
{
    const int w = blockIdx.z;
    const float* W = (w == 0) ? Wq : (w == 1) ? Wk : Wv;
    const float* B = (w == 0) ? Bq : (w == 1) ? Bk : Bv;
    float* O = out + (size_t)w * N_ROWS * DFEAT;

    __shared__ float As[32 * 34];   // [k][m], +2 pad
    __shared__ float Bs[32 * 34];   // [k][i], +2 pad

    const int t  = threadIdx.x;
    const int tx = t & 15;          // 0..15 -> output col pair
    const int ty = t >> 4;          // 0..15 -> output row pair
    const int row0 = blockIdx.y * 32;
    const int col0 = blockIdx.x * 32;

    const int lr = t >> 3;          // 0..31  tile row for loading
    const int lc = (t & 7) * 4;     // k-quad for loading

    float acc00 = 0.f, acc01 = 0.f, acc10 = 0.f, acc11 = 0.f;

    for (int k0 = 0; k0 < DFEAT; k0 += 32) {
        float4 a4 = *reinterpret_cast<const float4*>(
            X + (size_t)(row0 + lr) * DFEAT + k0 + lc);
        float4 b4 = *reinterpret_cast<const float4*>(
            W + (size_t)(col0 + lr) * DFEAT + k0 + lc);
        As[(lc + 0) * 34 + lr] = a4.x;
        As[(lc + 1) * 34 + lr] = a4.y;
        As[(lc + 2) * 34 + lr] = a4.z;
        As[(lc + 3) * 34 + lr] = a4.w;
        Bs[(lc + 0) * 34 + lr] = b4.x;
        Bs[(lc + 1) * 34 + lr] = b4.y;
        Bs[(lc + 2) * 34 + lr] = b4.z;
        Bs[(lc + 3) * 34 + lr] = b4.w;
        __syncthreads();

#pragma unroll
        for (int kk = 0; kk < 32; ++kk) {
            float2 a = *reinterpret_cast<const float2*>(&As[kk * 34 + 2 * ty]);
            float2 b = *reinterpret_cast<const float2*>(&Bs[kk * 34 + 2 * tx]);
            acc00 = fmaf(a.x, b.x, acc00);
            acc01 = fmaf(a.x, b.y, acc01);
            acc10 = fmaf(a.y, b.x, acc10);
            acc11 = fmaf(a.y, b.y, acc11);
        }
        __syncthreads();
    }

    const int r0 = row0 + 2 * ty;
    const int c0 = col0 + 2 * tx;
    const float b0 = B[c0];
    const float b1 = B[c0 + 1];
    O[(size_t)r0 * DFEAT + c0]           = acc00 + b0;
    O[(size_t)r0 * DFEAT + c0 + 1]       = acc01 + b1;
    O[(size_t)(r0 + 1) * DFEAT + c0]     = acc10 + b0;
    O[(size_t)(r0 + 1) * DFEAT + c0 + 1] = acc11 + b1;
}

// ---------------------------------------------------------------------------
// Kernel 2: rank-1 attention.
// Att[n,i] = sum_j exp(q_i*k_j)*v_j / sum_j exp(q_i*k_j)
// One block per row n; 192 threads; each thread handles i = t, t+192, t+384.
// No max-subtraction needed: |q*k| <~ 10 so exp stays well inside fp32 range.
// ---------------------------------------------------------------------------
__global__ __launch_bounds__(192) void attn_kernel(
    const float* __restrict__ qkv,          // Q | K | V, each 512x576 fp32
    float* __restrict__ out)                // 512x576 fp32
{
    const int n = blockIdx.x;
    const float* Q = qkv + (size_t)n * DFEAT;
    const float* K = qkv + (size_t)(N_ROWS + n) * DFEAT;
    const float* V = qkv + (size_t)(2 * N_ROWS + n) * DFEAT;

    __shared__ float2 kv[DFEAT];            // (k_j, v_j)

    const int t = threadIdx.x;
#pragma unroll
    for (int r = 0; r < 3; ++r) {
        int j = t + 192 * r;
        kv[j] = make_float2(K[j], V[j]);
    }
    __syncthreads();

    const float LOG2E = 1.4426950408889634f;
    const float ql0 = Q[t] * LOG2E;
    const float ql1 = Q[t + 192] * LOG2E;
    const float ql2 = Q[t + 384] * LOG2E;

    float s0 = 0.f, s1 = 0.f, s2 = 0.f;
    float a0 = 0.f, a1 = 0.f, a2 = 0.f;

#pragma unroll 4
    for (int j = 0; j < DFEAT; ++j) {
        float2 p = kv[j];
        float e0 = EXP2F(ql0 * p.x);
        float e1 = EXP2F(ql1 * p.x);
        float e2 = EXP2F(ql2 * p.x);
        s0 += e0; s1 += e1; s2 += e2;
        a0 = fmaf(e0, p.y, a0);
        a1 = fmaf(e1, p.y, a1);
        a2 = fmaf(e2, p.y, a2);
    }

    float* O = out + (size_t)n * DFEAT;
    O[t]       = a0 / s0;
    O[t + 192] = a1 / s1;
    O[t + 384] = a2 / s2;
}

// ---------------------------------------------------------------------------
extern "C" void kernel_launch(void* const* d_in, const int* in_sizes, int n_in,
                              void* d_out, int out_size, void* d_ws, size_t ws_size,
                              hipStream_t stream) {
    const float* x  = (const float*)d_in[0];
    const float* Wq = (const float*)d_in[1];
    const float* bq = (const float*)d_in[2];
    const float* Wk = (const float*)d_in[3];
    const float* bk = (const float*)d_in[4];
    const float* Wv = (const float*)d_in[5];
    const float* bv = (const float*)d_in[6];

    float* qkv = (float*)d_ws;              // 3 * 512 * 576 fp32 = 3.54 MB

    dim3 g1(DFEAT / 32, N_ROWS / 32, 3);    // 18 x 16 x 3
    qkv_gemm_kernel<<<g1, 256, 0, stream>>>(x, Wq, bq, Wk, bk, Wv, bv, qkv);

    attn_kernel<<<N_ROWS, 192, 0, stream>>>(qkv, (float*)d_out);
}

// Round 3
// 48.549 us; speedup vs baseline: 1.5846x; 1.5846x over previous
//
#include <hip/hip_runtime.h>
#include <hip/hip_bf16.h>

#define NR 512
#define DF 576

#if __has_builtin(__builtin_amdgcn_exp2f)
#define EXP2F __builtin_amdgcn_exp2f
#else
#define EXP2F exp2f
#endif

typedef short bf16x8 __attribute__((ext_vector_type(8)));
typedef float f32x4 __attribute__((ext_vector_type(4)));
typedef unsigned short u16x8 __attribute__((ext_vector_type(8)));

static __device__ __forceinline__ unsigned short f2bf(float f) {
    unsigned int u = __builtin_bit_cast(unsigned int, f);
    unsigned int r = u + 0x7FFFu + ((u >> 16) & 1u);
    return (unsigned short)(r >> 16);
}
static __device__ __forceinline__ float bf2f(unsigned short h) {
    unsigned int u = ((unsigned int)h) << 16;
    return __builtin_bit_cast(float, u);
}

// ---------------------------------------------------------------------------
// Kernel 1: QKV GEMM via bf16 MFMA with hi/lo fp32 split.
// OUT[w][n][i] = sum_k X[n,k]*W_w[i,k] + b_w[i], fp32 in/out.
// X ~= Xh+Xl (bf16 each); X*W^T ~= Xh*Wh + Xh*Wl + Xl*Wh  (err ~2^-16 rel).
// 64x64 tile, BK=64, 256 thr = 4 waves (2x2), each wave 32x32 via 2x2 frags
// of mfma_f32_16x16x32_bf16.  Reg-staged conversion + XOR-swizzled LDS.
// ---------------------------------------------------------------------------
__global__ __launch_bounds__(256) void qkv_mfma_kernel(
    const float* __restrict__ X,
    const float* __restrict__ Wq, const float* __restrict__ Bq,
    const float* __restrict__ Wk, const float* __restrict__ Bk,
    const float* __restrict__ Wv, const float* __restrict__ Bv,
    float* __restrict__ out)
{
    const int w = blockIdx.z;
    const float* W  = (w == 0) ? Wq : (w == 1) ? Wk : Wv;
    const float* Bi = (w == 0) ? Bq : (w == 1) ? Bk : Bv;
    float* O = out + (size_t)w * NR * DF;

    __shared__ unsigned short sm[16384];          // 32 KB: AH|AL|BH|BL 64x64 bf16
    unsigned short* const AH = sm;
    unsigned short* const AL = sm + 4096;
    unsigned short* const BH = sm + 8192;
    unsigned short* const BL = sm + 12288;

    const int tid  = threadIdx.x;
    const int lane = tid & 63;
    const int wv   = tid >> 6;                    // wave 0..3
    const int wr   = wv >> 1, wc = wv & 1;        // 2x2 wave grid

    const int brow0 = blockIdx.y * 64;
    const int bcol0 = blockIdx.x * 64;

    const int srow = tid >> 2;                    // staging row 0..63
    const int scol = (tid & 3) * 16;              // staging col 0/16/32/48
    const unsigned int sswz = (srow & 7) << 3;    // swizzle (ushort units)

    f32x4 acc[2][2] = {};

    for (int kt = 0; kt < DF; kt += 64) {
        const float* ga = X + (size_t)(brow0 + srow) * DF + kt + scol;
        const float* gb = W + (size_t)(bcol0 + srow) * DF + kt + scol;
        float4 av[4], bv4[4];
#pragma unroll
        for (int g = 0; g < 4; ++g) {
            av[g]  = *reinterpret_cast<const float4*>(ga + 4 * g);
            bv4[g] = *reinterpret_cast<const float4*>(gb + 4 * g);
        }
        float fa[16], fb[16];
#pragma unroll
        for (int g = 0; g < 4; ++g) {
            fa[4*g+0] = av[g].x;  fa[4*g+1] = av[g].y;  fa[4*g+2] = av[g].z;  fa[4*g+3] = av[g].w;
            fb[4*g+0] = bv4[g].x; fb[4*g+1] = bv4[g].y; fb[4*g+2] = bv4[g].z; fb[4*g+3] = bv4[g].w;
        }
        u16x8 ah0, ah1, al0, al1, bh0, bh1, bl0, bl1;
#pragma unroll
        for (int e = 0; e < 8; ++e) {
            unsigned short h;
            h = f2bf(fa[e]);     ah0[e] = h; al0[e] = f2bf(fa[e]     - bf2f(h));
            h = f2bf(fa[e + 8]); ah1[e] = h; al1[e] = f2bf(fa[e + 8] - bf2f(h));
            h = f2bf(fb[e]);     bh0[e] = h; bl0[e] = f2bf(fb[e]     - bf2f(h));
            h = f2bf(fb[e + 8]); bh1[e] = h; bl1[e] = f2bf(fb[e + 8] - bf2f(h));
        }
        __syncthreads();                          // prev tile fully consumed
        const int base = srow * 64;
        *reinterpret_cast<u16x8*>(&AH[base + ((scol    ) ^ sswz)]) = ah0;
        *reinterpret_cast<u16x8*>(&AH[base + ((scol + 8) ^ sswz)]) = ah1;
        *reinterpret_cast<u16x8*>(&AL[base + ((scol    ) ^ sswz)]) = al0;
        *reinterpret_cast<u16x8*>(&AL[base + ((scol + 8) ^ sswz)]) = al1;
        *reinterpret_cast<u16x8*>(&BH[base + ((scol    ) ^ sswz)]) = bh0;
        *reinterpret_cast<u16x8*>(&BH[base + ((scol + 8) ^ sswz)]) = bh1;
        *reinterpret_cast<u16x8*>(&BL[base + ((scol    ) ^ sswz)]) = bl0;
        *reinterpret_cast<u16x8*>(&BL[base + ((scol + 8) ^ sswz)]) = bl1;
        __syncthreads();                          // tile visible

#pragma unroll
        for (int ks = 0; ks < 2; ++ks) {
            const int k0 = ks * 32 + (lane >> 4) * 8;
            bf16x8 fah[2], fal[2], fbh[2], fbl[2];
#pragma unroll
            for (int mi = 0; mi < 2; ++mi) {
                const int r   = wr * 32 + mi * 16 + (lane & 15);
                const int idx = r * 64 + (k0 ^ ((r & 7) << 3));
                fah[mi] = *reinterpret_cast<const bf16x8*>(&AH[idx]);
                fal[mi] = *reinterpret_cast<const bf16x8*>(&AL[idx]);
            }
#pragma unroll
            for (int ni = 0; ni < 2; ++ni) {
                const int r   = wc * 32 + ni * 16 + (lane & 15);
                const int idx = r * 64 + (k0 ^ ((r & 7) << 3));
                fbh[ni] = *reinterpret_cast<const bf16x8*>(&BH[idx]);
                fbl[ni] = *reinterpret_cast<const bf16x8*>(&BL[idx]);
            }
#pragma unroll
            for (int mi = 0; mi < 2; ++mi)
#pragma unroll
                for (int ni = 0; ni < 2; ++ni) {
                    acc[mi][ni] = __builtin_amdgcn_mfma_f32_16x16x32_bf16(fah[mi], fbh[ni], acc[mi][ni], 0, 0, 0);
                    acc[mi][ni] = __builtin_amdgcn_mfma_f32_16x16x32_bf16(fah[mi], fbl[ni], acc[mi][ni], 0, 0, 0);
                    acc[mi][ni] = __builtin_amdgcn_mfma_f32_16x16x32_bf16(fal[mi], fbh[ni], acc[mi][ni], 0, 0, 0);
                }
        }
    }

    // epilogue: D col = lane&15, row = (lane>>4)*4 + reg  (m89-verified map)
#pragma unroll
    for (int ni = 0; ni < 2; ++ni) {
        const int col  = bcol0 + wc * 32 + ni * 16 + (lane & 15);
        const float bias = Bi[col];
#pragma unroll
        for (int mi = 0; mi < 2; ++mi) {
            const int row0 = brow0 + wr * 32 + mi * 16 + (lane >> 4) * 4;
#pragma unroll
            for (int r = 0; r < 4; ++r)
                O[(size_t)(row0 + r) * DF + col] = acc[mi][ni][r] + bias;
        }
    }
}

// ---------------------------------------------------------------------------
// Kernel 2: rank-1 attention.  Att[n,i] = sum_j exp(q_i k_j) v_j / sum_j exp(q_i k_j)
// 576 threads (9 waves) per row n; one output column per thread; dual accums.
// No max-subtraction: |q*k| <~ 10, fp32-safe, softmax shift-invariant.
// ---------------------------------------------------------------------------
__global__ __launch_bounds__(576) void attn_kernel(
    const float* __restrict__ qkv,          // Q | K | V, each 512x576 fp32
    float* __restrict__ out)
{
    const int n = blockIdx.x;
    const float* Q = qkv + (size_t)n * DF;
    const float* K = qkv + (size_t)(NR + n) * DF;
    const float* V = qkv + (size_t)(2 * NR + n) * DF;

    __shared__ float2 kv[DF];
    const int t = threadIdx.x;
    kv[t] = make_float2(K[t], V[t]);
    __syncthreads();

    const float ql = Q[t] * 1.4426950408889634f;
    float s0 = 0.f, s1 = 0.f, a0 = 0.f, a1 = 0.f;
#pragma unroll 4
    for (int j = 0; j < DF; j += 2) {
        float2 p0 = kv[j];
        float2 p1 = kv[j + 1];
        float e0 = EXP2F(ql * p0.x);
        float e1 = EXP2F(ql * p1.x);
        s0 += e0; s1 += e1;
        a0 = fmaf(e0, p0.y, a0);
        a1 = fmaf(e1, p1.y, a1);
    }
    out[(size_t)n * DF + t] = (a0 + a1) / (s0 + s1);
}

// ---------------------------------------------------------------------------
extern "C" void kernel_launch(void* const* d_in, const int* in_sizes, int n_in,
                              void* d_out, int out_size, void* d_ws, size_t ws_size,
                              hipStream_t stream) {
    const float* x  = (const float*)d_in[0];
    const float* Wq = (const float*)d_in[1];
    const float* bq = (const float*)d_in[2];
    const float* Wk = (const float*)d_in[3];
    const float* bk = (const float*)d_in[4];
    const float* Wv = (const float*)d_in[5];
    const float* bv = (const float*)d_in[6];

    float* qkv = (float*)d_ws;              // 3 * 512 * 576 fp32 = 3.54 MB

    dim3 g1(DF / 64, NR / 64, 3);           // 9 x 8 x 3 = 216 blocks
    qkv_mfma_kernel<<<g1, 256, 0, stream>>>(x, Wq, bq, Wk, bk, Wv, bv, qkv);

    attn_kernel<<<NR, DF, 0, stream>>>(qkv, (float*)d_out);
}

// Round 4
// 43.342 us; speedup vs baseline: 1.7749x; 1.1201x over previous
//
#include <hip/hip_runtime.h>
#include <hip/hip_bf16.h>

#define NR 512
#define DF 576

#if __has_builtin(__builtin_amdgcn_exp2f)
#define EXP2F __builtin_amdgcn_exp2f
#else
#define EXP2F exp2f
#endif

typedef short bf16x8 __attribute__((ext_vector_type(8)));
typedef float f32x4 __attribute__((ext_vector_type(4)));
typedef unsigned short u16x8 __attribute__((ext_vector_type(8)));

static __device__ __forceinline__ unsigned short f2bf(float f) {
    unsigned int u = __builtin_bit_cast(unsigned int, f);
    unsigned int r = u + 0x7FFFu + ((u >> 16) & 1u);
    return (unsigned short)(r >> 16);
}
static __device__ __forceinline__ float bf2f(unsigned short h) {
    return __builtin_bit_cast(float, ((unsigned int)h) << 16);
}

// Workspace layout (bytes):
//  0        : qkv fp32, 3*512*576 floats             (3,538,944 B)
//  3538944  : Xh  512*576 u16                        (589,824 B)
//  4128768  : Xl  512*576 u16                        (589,824 B)
//  4718592  : Wh  3*576*576 u16                      (1,990,656 B)
//  6709248  : Wl  3*576*576 u16                      (1,990,656 B)
#define QKV_OFF 0
#define XH_OFF  3538944
#define XL_OFF  4128768
#define WH_OFF  4718592
#define WL_OFF  6709248

// ---------------------------------------------------------------------------
// Kernel 0: one-time (per launch) fp32 -> bf16 hi/lo plane conversion.
// blockIdx.y: 0 -> X, 1..3 -> Wq/Wk/Wv.
// ---------------------------------------------------------------------------
__global__ __launch_bounds__(256) void prep_hilo_kernel(
    const float* __restrict__ X,
    const float* __restrict__ Wq, const float* __restrict__ Wk,
    const float* __restrict__ Wv,
    unsigned short* __restrict__ Xh, unsigned short* __restrict__ Xl,
    unsigned short* __restrict__ Wh, unsigned short* __restrict__ Wl)
{
    const int z = blockIdx.y;
    const float* src; unsigned short *dh, *dl; int n4;
    if (z == 0)      { src = X;  dh = Xh; dl = Xl; n4 = (NR * DF) / 4; }
    else {
        src = (z == 1) ? Wq : (z == 2) ? Wk : Wv;
        const size_t base = (size_t)(z - 1) * DF * DF;
        dh = Wh + base; dl = Wl + base; n4 = (DF * DF) / 4;
    }
    const int i = blockIdx.x * 256 + threadIdx.x;
    if (i >= n4) return;
    float4 v = reinterpret_cast<const float4*>(src)[i];
    ushort4 h, l;
    h.x = f2bf(v.x); l.x = f2bf(v.x - bf2f(h.x));
    h.y = f2bf(v.y); l.y = f2bf(v.y - bf2f(h.y));
    h.z = f2bf(v.z); l.z = f2bf(v.z - bf2f(h.z));
    h.w = f2bf(v.w); l.w = f2bf(v.w - bf2f(h.w));
    reinterpret_cast<ushort4*>(dh)[i] = h;
    reinterpret_cast<ushort4*>(dl)[i] = l;
}

// ---------------------------------------------------------------------------
// Kernel 1: QKV GEMM from bf16 hi/lo planes.
// OUT[w][n][i] = sum_k X[n,k]*W_w[i,k] + b_w[i]   (err ~2^-16 via 3-term split)
// BM=BN=32, BK=64, 4 waves (2x2), each wave one 16x16 frag, full K.
// Grid 18x16x3 = 864 blocks (~3.4/CU) for latency hiding.
// ---------------------------------------------------------------------------
__global__ __launch_bounds__(256) void qkv_mfma2_kernel(
    const unsigned short* __restrict__ Xh, const unsigned short* __restrict__ Xl,
    const unsigned short* __restrict__ Wh, const unsigned short* __restrict__ Wl,
    const float* __restrict__ Bq, const float* __restrict__ Bk,
    const float* __restrict__ Bv,
    float* __restrict__ out)
{
    const int w = blockIdx.z;
    const float* Bi = (w == 0) ? Bq : (w == 1) ? Bk : Bv;
    const unsigned short* WhP = Wh + (size_t)w * DF * DF;
    const unsigned short* WlP = Wl + (size_t)w * DF * DF;
    float* O = out + (size_t)w * NR * DF;

    __shared__ __align__(16) unsigned short Ah[32 * 64];
    __shared__ __align__(16) unsigned short Al[32 * 64];
    __shared__ __align__(16) unsigned short Bh[32 * 64];
    __shared__ __align__(16) unsigned short Bl[32 * 64];

    const int tid  = threadIdx.x;
    const int lane = tid & 63;
    const int wv   = tid >> 6;
    const int wr   = wv >> 1, wc = wv & 1;
    const int brow0 = blockIdx.y * 32;
    const int bcol0 = blockIdx.x * 32;

    const int srow = tid >> 3;            // 0..31
    const int scol = (tid & 7) * 8;       // 0..56
    const int sidx = srow * 64 + (scol ^ ((srow & 7) << 3));
    const size_t ga = (size_t)(brow0 + srow) * DF + scol;
    const size_t gb = (size_t)(bcol0 + srow) * DF + scol;

    // precompute frag read indices
    const int ar = wr * 16 + (lane & 15);
    const int br = wc * 16 + (lane & 15);
    const int kq = (lane >> 4) * 8;
    const int aswz = (ar & 7) << 3;
    const int bswz = (br & 7) << 3;

    f32x4 acc = {0.f, 0.f, 0.f, 0.f};

    for (int kt = 0; kt < DF; kt += 64) {
        u16x8 xh = *reinterpret_cast<const u16x8*>(Xh  + ga + kt);
        u16x8 xl = *reinterpret_cast<const u16x8*>(Xl  + ga + kt);
        u16x8 wh = *reinterpret_cast<const u16x8*>(WhP + gb + kt);
        u16x8 wl = *reinterpret_cast<const u16x8*>(WlP + gb + kt);
        __syncthreads();                  // prev tile consumed
        *reinterpret_cast<u16x8*>(&Ah[sidx]) = xh;
        *reinterpret_cast<u16x8*>(&Al[sidx]) = xl;
        *reinterpret_cast<u16x8*>(&Bh[sidx]) = wh;
        *reinterpret_cast<u16x8*>(&Bl[sidx]) = wl;
        __syncthreads();                  // tile visible

#pragma unroll
        for (int ks = 0; ks < 2; ++ks) {
            const int k0 = ks * 32 + kq;
            bf16x8 fah = *reinterpret_cast<const bf16x8*>(&Ah[ar * 64 + (k0 ^ aswz)]);
            bf16x8 fal = *reinterpret_cast<const bf16x8*>(&Al[ar * 64 + (k0 ^ aswz)]);
            bf16x8 fbh = *reinterpret_cast<const bf16x8*>(&Bh[br * 64 + (k0 ^ bswz)]);
            bf16x8 fbl = *reinterpret_cast<const bf16x8*>(&Bl[br * 64 + (k0 ^ bswz)]);
            acc = __builtin_amdgcn_mfma_f32_16x16x32_bf16(fah, fbh, acc, 0, 0, 0);
            acc = __builtin_amdgcn_mfma_f32_16x16x32_bf16(fah, fbl, acc, 0, 0, 0);
            acc = __builtin_amdgcn_mfma_f32_16x16x32_bf16(fal, fbh, acc, 0, 0, 0);
        }
    }

    const int col  = bcol0 + wc * 16 + (lane & 15);
    const float bias = Bi[col];
    const int row0 = brow0 + wr * 16 + (lane >> 4) * 4;
#pragma unroll
    for (int r = 0; r < 4; ++r)
        O[(size_t)(row0 + r) * DF + col] = acc[r] + bias;
}

// ---------------------------------------------------------------------------
// Kernel 2: rank-1 attention.
// Att[n,i] = sum_j exp(q_i k_j) v_j / sum_j exp(q_i k_j)
// 576 threads per row n, one output column per thread.  K/V in separate LDS
// arrays, float2 loads, two independent accumulator chains.
// No max-subtraction: |q*k| <~ 10, fp32-safe (softmax shift-invariant).
// ---------------------------------------------------------------------------
__global__ __launch_bounds__(576) void attn_kernel(
    const float* __restrict__ qkv,
    float* __restrict__ out)
{
    const int n = blockIdx.x;
    const float* Q = qkv + (size_t)n * DF;
    const float* K = qkv + (size_t)(NR + n) * DF;
    const float* V = qkv + (size_t)(2 * NR + n) * DF;

    __shared__ __align__(16) float Ks[DF];
    __shared__ __align__(16) float Vs[DF];

    const int t = threadIdx.x;
    Ks[t] = K[t];
    Vs[t] = V[t];
    const float ql = Q[t] * 1.4426950408889634f;
    __syncthreads();

    const float2* Kp = reinterpret_cast<const float2*>(Ks);
    const float2* Vp = reinterpret_cast<const float2*>(Vs);

    float s0 = 0.f, s1 = 0.f, a0 = 0.f, a1 = 0.f;
#pragma unroll 8
    for (int j = 0; j < DF / 2; ++j) {
        float2 kk = Kp[j];
        float2 vv = Vp[j];
        float e0 = EXP2F(ql * kk.x);
        float e1 = EXP2F(ql * kk.y);
        s0 += e0; s1 += e1;
        a0 = fmaf(e0, vv.x, a0);
        a1 = fmaf(e1, vv.y, a1);
    }
    out[(size_t)n * DF + t] = (a0 + a1) / (s0 + s1);
}

// ---------------------------------------------------------------------------
extern "C" void kernel_launch(void* const* d_in, const int* in_sizes, int n_in,
                              void* d_out, int out_size, void* d_ws, size_t ws_size,
                              hipStream_t stream) {
    const float* x  = (const float*)d_in[0];
    const float* Wq = (const float*)d_in[1];
    const float* bq = (const float*)d_in[2];
    const float* Wk = (const float*)d_in[3];
    const float* bk = (const float*)d_in[4];
    const float* Wv = (const float*)d_in[5];
    const float* bv = (const float*)d_in[6];

    char* ws = (char*)d_ws;
    float*          qkv = (float*)(ws + QKV_OFF);
    unsigned short* Xh  = (unsigned short*)(ws + XH_OFF);
    unsigned short* Xl  = (unsigned short*)(ws + XL_OFF);
    unsigned short* Wh  = (unsigned short*)(ws + WH_OFF);
    unsigned short* Wl  = (unsigned short*)(ws + WL_OFF);

    // prep: max(73728, 82944) float4 per z / 256 thr -> 324 blocks
    prep_hilo_kernel<<<dim3(324, 4, 1), 256, 0, stream>>>(
        x, Wq, Wk, Wv, Xh, Xl, Wh, Wl);

    dim3 g1(DF / 32, NR / 32, 3);   // 18 x 16 x 3 = 864 blocks
    qkv_mfma2_kernel<<<g1, 256, 0, stream>>>(
        Xh, Xl, Wh, Wl, bq, bk, bv, qkv);

    attn_kernel<<<NR, DF, 0, stream>>>(qkv, (float*)d_out);
}